// Round 1
// 884.107 us; speedup vs baseline: 1.0362x; 1.0362x over previous
//
#include <hip/hip_runtime.h>
#include <hip/hip_bf16.h>
#include <stdint.h>

// ---------------- problem constants ----------------
constexpr int NT = 8192;   // tokens (B*S)
constexpr int NE = 8;      // experts
constexpr int ND = 1024;   // d_model
constexpr int NH = 4096;   // hidden

constexpr int TM = 128;    // block tile M
constexpr int TN = 256;    // block tile N (8 waves: 2x4 of 64x64)
constexpr int BK = 32;     // K tile
constexpr int KS_DN = 2;   // split-K factor for down GEMM (occupancy)

typedef __attribute__((ext_vector_type(8))) short short8;  // 8 bf16 (4 VGPRs)
typedef __attribute__((ext_vector_type(4))) float f32x4;

// ---------------- workspace layout (bytes) ----------------
constexpr size_t O_XBF  = 0;                                   // x bf16 [NT][ND]
constexpr size_t O_WUPT = O_XBF  + (size_t)NT * ND * 2;        // w_up^T bf16 [E][H][D]
constexpr size_t O_WDNT = O_WUPT + (size_t)NE * NH * ND * 2;   // w_down^T bf16 [E][D][H]
constexpr size_t O_HBUF = O_WDNT + (size_t)NE * ND * NH * 2;   // hidden bf16 [NT*2][NH]
constexpr size_t O_STOK = O_HBUF + (size_t)NT * 2 * NH * 2;    // slot -> token
constexpr size_t O_SP   = O_STOK + (size_t)NT * 2 * 4;         // slot -> gate p
constexpr size_t O_TKE  = O_SP   + (size_t)NT * 2 * 4;         // token -> top2 experts
constexpr size_t O_TKP  = O_TKE  + (size_t)NT * 2 * 4;         // token -> top2 probs
constexpr size_t O_CTRL = O_TKP  + (size_t)NT * 2 * 4;
// ctrl: cnt[16]@0 fill[16]@64 probsum[8]@128 off[16]@192 ntiles[2]@256
constexpr size_t O_TLUP = O_CTRL + 272;                        // int[160] tile list up
constexpr size_t O_TLDN = O_TLUP + 160 * 4;                    // int[160] tile list down

__device__ __forceinline__ void gl_lds16(const void* g, void* l) {
  using GP = char __attribute__((address_space(1))) *;
  using LP = char __attribute__((address_space(3))) *;
  __builtin_amdgcn_global_load_lds((GP)(uintptr_t)g, (LP)(uint32_t)(uintptr_t)l, 16, 0, 0);
}

__device__ __forceinline__ float fast_gelu(float x) {
  float u  = 0.7978845608028654f * (x + 0.044715f * x * x * x);
  float ex = __expf(2.0f * u);
  float th = 1.0f - 2.0f / (ex + 1.0f);
  return 0.5f * x * (1.0f + th);
}

// ---------------- router: logits, softmax, top2, counts; also x->bf16 ----------------
__global__ __launch_bounds__(256) void moe_router(
    const float* __restrict__ x, const float* __restrict__ rw, const float* __restrict__ rb,
    __hip_bfloat16* __restrict__ xbf,
    float* __restrict__ probs_out, int* __restrict__ topk_e, float* __restrict__ topk_p,
    int* __restrict__ cnt_ek, float* __restrict__ probsum)
{
  __shared__ float ps[NE];
  __shared__ int cs[16];
  const int tid = threadIdx.x;
  if (tid < NE) ps[tid] = 0.f;
  if (tid < 16) cs[tid] = 0;
  __syncthreads();
  const int lane = tid & 63, wv = tid >> 6;
  for (int it = 0; it < 8; ++it) {
    const int t = blockIdx.x * 4 + wv + it * 1024;
    const float* xr = x + (size_t)t * ND;
    float acc[NE] = {};
#pragma unroll 4
    for (int j = 0; j < 16; ++j) {
      const int d = j * 64 + lane;
      const float xv = xr[d];
      xbf[(size_t)t * ND + d] = __float2bfloat16(xv);
      const float* w = rw + (size_t)d * NE;
#pragma unroll
      for (int ee = 0; ee < NE; ++ee) acc[ee] += xv * w[ee];
    }
#pragma unroll
    for (int ee = 0; ee < NE; ++ee)
#pragma unroll
      for (int off = 32; off >= 1; off >>= 1)
        acc[ee] += __shfl_down(acc[ee], off, 64);
    if (lane == 0) {
      float lg[NE];
#pragma unroll
      for (int ee = 0; ee < NE; ++ee) lg[ee] = acc[ee] + rb[ee];
      float mx = lg[0];
#pragma unroll
      for (int ee = 1; ee < NE; ++ee) mx = fmaxf(mx, lg[ee]);
      float s = 0.f, pe[NE];
#pragma unroll
      for (int ee = 0; ee < NE; ++ee) { pe[ee] = __expf(lg[ee] - mx); s += pe[ee]; }
      const float inv = 1.f / s;
#pragma unroll
      for (int ee = 0; ee < NE; ++ee) {
        const float pr = pe[ee] * inv;
        probs_out[(size_t)t * NE + ee] = pr;
        atomicAdd(&ps[ee], pr);
      }
      int i1 = 0; float l1 = lg[0];
#pragma unroll
      for (int ee = 1; ee < NE; ++ee) if (lg[ee] > l1) { l1 = lg[ee]; i1 = ee; }
      int i2 = 0; float l2 = -3.0e38f;
#pragma unroll
      for (int ee = 0; ee < NE; ++ee) if (ee != i1 && lg[ee] > l2) { l2 = lg[ee]; i2 = ee; }
      const float e2 = __expf(l2 - l1);
      const float dn = 1.f + e2;
      topk_e[t * 2]     = i1;  topk_e[t * 2 + 1] = i2;
      topk_p[t * 2]     = 1.f / dn;
      topk_p[t * 2 + 1] = e2 / dn;
      atomicAdd(&cs[i1 * 2], 1);
      atomicAdd(&cs[i2 * 2 + 1], 1);
    }
  }
  __syncthreads();
  if (tid < NE) atomicAdd(&probsum[tid], ps[tid]);
  if (tid < 16) atomicAdd(&cnt_ek[tid], cs[tid]);
}

// ---------------- offsets prefix + aux loss + tile lists (lane-parallel writes) ----------
__global__ void moe_finalize(const int* __restrict__ cnt_ek, int* __restrict__ off_ek,
                             const float* __restrict__ probsum, float* __restrict__ aux_out,
                             int* __restrict__ ntiles, int* __restrict__ tl_up,
                             int* __restrict__ tl_dn)
{
  __shared__ int c[16], off[16], uoff[8], ucnt[8], doff[16], dcnt[16];
  const int tid = threadIdx.x;
  if (tid < 16) c[tid] = cnt_ek[tid];
  __syncthreads();
  if (tid == 0) {
    int run = 0;
    for (int i = 0; i < 16; ++i) { off[i] = run; run += c[i]; }
    int ur = 0;
    for (int e = 0; e < NE; ++e) {
      ucnt[e] = (c[2 * e] + c[2 * e + 1] + TM - 1) / TM;
      uoff[e] = ur; ur += ucnt[e];
    }
    ntiles[0] = ur;
    int dr = 0;
    for (int i = 0; i < 16; ++i) {
      dcnt[i] = (c[i] + TM - 1) / TM;
      doff[i] = dr; dr += dcnt[i];
    }
    ntiles[1] = dr;
    float aux = 0.f;
    for (int e = 0; e < NE; ++e) {
      float frac = (float)(c[2 * e] + c[2 * e + 1]) / (float)(NT * 2);
      aux += frac * (probsum[e] / (float)NT);
    }
    aux_out[0] = (float)NE * aux * 0.01f;
  }
  __syncthreads();
  if (tid < 16) off_ek[tid] = off[tid];
  if (tid < 8)
    for (int mb = 0; mb < ucnt[tid]; ++mb) tl_up[uoff[tid] + mb] = (tid << 16) | mb;
  if (tid >= 32 && tid < 48) {
    const int i = tid - 32;
    for (int mb = 0; mb < dcnt[i]; ++mb) tl_dn[doff[i] + mb] = (i << 16) | mb;
  }
}

// ---------------- scatter: per-block LDS histogram, 16 global atomics/block ----------
__global__ __launch_bounds__(256) void moe_scatter(
    const int* __restrict__ topk_e, const float* __restrict__ topk_p,
    const int* __restrict__ off_ek, int* __restrict__ fill_ek,
    int* __restrict__ slot_token, float* __restrict__ slot_p)
{
  __shared__ int lc[16], gb[16], offs[16];
  const int tid = threadIdx.x;
  if (tid < 16) lc[tid] = 0;
  __syncthreads();
  const int t = blockIdx.x * 256 + tid;
  const int id0 = topk_e[t * 2] * 2;
  const int id1 = topk_e[t * 2 + 1] * 2 + 1;
  atomicAdd(&lc[id0], 1);
  atomicAdd(&lc[id1], 1);
  __syncthreads();
  if (tid < 16) {
    gb[tid] = atomicAdd(&fill_ek[tid], lc[tid]);
    offs[tid] = off_ek[tid];
    lc[tid] = 0;
  }
  __syncthreads();
  {
    const int r = atomicAdd(&lc[id0], 1);
    const int slot = offs[id0] + gb[id0] + r;
    slot_token[slot] = t;
    slot_p[slot] = topk_p[t * 2];
  }
  {
    const int r = atomicAdd(&lc[id1], 1);
    const int slot = offs[id1] + gb[id1] + r;
    slot_token[slot] = t;
    slot_p[slot] = topk_p[t * 2 + 1];
  }
}

// ---------------- transpose+cast: in fp32 [E][A][B] -> out bf16 [E][B][A] ----------------
__global__ __launch_bounds__(256) void moe_transpose_cast(
    const float* __restrict__ in, __hip_bfloat16* __restrict__ outp, int Adim, int Bdim)
{
  __shared__ unsigned short tile[64 * 66];
  const int e = blockIdx.z;
  const int b0 = blockIdx.x * 64, a0 = blockIdx.y * 64;
  const float* ip = in + (size_t)e * Adim * Bdim + (size_t)a0 * Bdim + b0;
  const int c4 = (threadIdx.x & 15) * 4;
  const int r0 = threadIdx.x >> 4;
#pragma unroll
  for (int i = 0; i < 4; ++i) {
    const int r = r0 + i * 16;
    const float4 v = *(const float4*)(ip + (size_t)r * Bdim + c4);
    ushort4 u;
    u.x = __hip_bfloat16_raw(__float2bfloat16(v.x)).x;
    u.y = __hip_bfloat16_raw(__float2bfloat16(v.y)).x;
    u.z = __hip_bfloat16_raw(__float2bfloat16(v.z)).x;
    u.w = __hip_bfloat16_raw(__float2bfloat16(v.w)).x;
    *(ushort4*)&tile[r * 66 + c4] = u;
  }
  __syncthreads();
  unsigned short* op = (unsigned short*)outp + (size_t)e * Bdim * Adim + (size_t)b0 * Adim + a0;
  const int cc  = threadIdx.x >> 2;
  const int rr0 = (threadIdx.x & 3) * 16;
  unsigned short u[16];
#pragma unroll
  for (int i = 0; i < 16; ++i) u[i] = tile[(rr0 + i) * 66 + cc];
  *(short8*)(op + (size_t)cc * Adim + rr0)     = *(short8*)&u[0];
  *(short8*)(op + (size_t)cc * Adim + rr0 + 8) = *(short8*)&u[8];
}

// ---------------- grouped GEMM 1: H = gelu(X_sel @ w_up + b_up) ----------------
// 128x256 tile, 8 waves (2x4 of 64x64), 16x16x32 bf16 MFMA, BK=32.
// NEW (this round): double-buffered LDS 2-phase pipeline (T3 minimum):
//   stage tile t+1 -> compute tile t -> one barrier per K-step.
// LDS chunk swizzle unchanged (measured 0 conflicts): slot (row,c) holds
// global chunk c ^ ((row>>1)&3); 64 B row stride.
__global__ __launch_bounds__(512, 4) void moe_gemm_up(
    const __hip_bfloat16* __restrict__ xbf,
    const __hip_bfloat16* __restrict__ wupT,   // [E][H][D]
    const float* __restrict__ b_up,
    const int* __restrict__ slot_token,
    const int* __restrict__ cnt_ek, const int* __restrict__ off_ek,
    const int* __restrict__ ntiles, const int* __restrict__ tl_up,
    __hip_bfloat16* __restrict__ hbuf)          // [NT*2][NH]
{
  if ((int)blockIdx.y >= ntiles[0]) return;
  const int tl = tl_up[blockIdx.y];
  const int e = tl >> 16, mb = tl & 0xffff;
  const int cnt = cnt_ek[2 * e] + cnt_ek[2 * e + 1];
  const int base = off_ek[2 * e];
  const int m0 = mb * TM;
  const int n0 = blockIdx.x * TN;
  const int valid = (cnt - m0 < TM) ? (cnt - m0) : TM;

  __shared__ __align__(16) __hip_bfloat16 As0[TM * BK], As1[TM * BK];   // 2x8 KB
  __shared__ __align__(16) __hip_bfloat16 Bs0[TN * BK], Bs1[TN * BK];   // 2x16 KB

  const int tid = threadIdx.x;
  const int lane = tid & 63, wv = tid >> 6;

  // A: 512 chunks (1/thread); B: 1024 chunks (2/thread)
  const int raA = tid >> 2;
  const int kcA = ((tid & 3) ^ ((raA >> 1) & 3)) * 8;
  int srA = m0 + raA; if (srA >= cnt) srA = cnt - 1;
  const __hip_bfloat16* ga = xbf + (size_t)slot_token[base + srA] * ND + kcA;
  const __hip_bfloat16* gb0;
  const __hip_bfloat16* gb1;
  {
    const int r0 = tid >> 2;
    const int k0 = ((tid & 3) ^ ((r0 >> 1) & 3)) * 8;
    gb0 = wupT + ((size_t)e * NH + n0 + r0) * ND + k0;
    const int ci = tid + 512;
    const int r1 = ci >> 2;
    const int k1 = ((ci & 3) ^ ((r1 >> 1) & 3)) * 8;
    gb1 = wupT + ((size_t)e * NH + n0 + r1) * ND + k1;
  }
  char* lA0 = (char*)As0 + tid * 16;
  char* lA1 = (char*)As1 + tid * 16;
  char* lB0 = (char*)Bs0 + tid * 16;
  char* lB1 = (char*)Bs1 + tid * 16;

  const int wm = (wv >> 2) * 64, wn = (wv & 3) * 64;
  const int l15 = lane & 15, q = lane >> 4;
  const int ssw = (q ^ ((l15 >> 1) & 3)) * 16;
  const char* rA0 = (const char*)As0 + (wm + l15) * 64 + ssw;
  const char* rA1 = (const char*)As1 + (wm + l15) * 64 + ssw;
  const char* rB0 = (const char*)Bs0 + (wn + l15) * 64 + ssw;
  const char* rB1 = (const char*)Bs1 + (wn + l15) * 64 + ssw;

  f32x4 acc[4][4] = {};

  auto STAGE = [&](char* sA, char* sB, int kk) {
    gl_lds16(ga + kk, sA);
    gl_lds16(gb0 + kk, sB);
    gl_lds16(gb1 + kk, sB + 8192);
  };
  auto COMPUTE = [&](const char* bA, const char* bB) {
    short8 af[4], bfr[4];
#pragma unroll
    for (int i = 0; i < 4; ++i) af[i]  = *(const short8*)(bA + i * 1024);
#pragma unroll
    for (int i = 0; i < 4; ++i) bfr[i] = *(const short8*)(bB + i * 1024);
#pragma unroll
    for (int mt = 0; mt < 4; ++mt)
#pragma unroll
      for (int nt = 0; nt < 4; ++nt)
        acc[mt][nt] = __builtin_amdgcn_mfma_f32_16x16x32_bf16(af[mt], bfr[nt], acc[mt][nt], 0, 0, 0);
  };

  // prologue: fill buffer 0 (barrier drains vmcnt(0))
  STAGE(lA0, lB0, 0);
  __syncthreads();

  // ND/BK = 32 steps, unrolled by 2 for static buffer addressing
  for (int kk = 0; kk < ND; kk += 2 * BK) {
    STAGE(lA1, lB1, kk + BK);           // next tile -> buf1 (overlaps compute)
    COMPUTE(rA0, rB0);                  // compute buf0
    __syncthreads();                    // drains vmcnt(0): buf1 ready, buf0 free
    if (kk + 2 * BK < ND) STAGE(lA0, lB0, kk + 2 * BK);
    COMPUTE(rA1, rB1);
    __syncthreads();
  }

  float bias[4];
#pragma unroll
  for (int nt = 0; nt < 4; ++nt) bias[nt] = b_up[e * NH + n0 + wn + nt * 16 + l15];
#pragma unroll
  for (int mt = 0; mt < 4; ++mt) {
#pragma unroll
    for (int rr = 0; rr < 4; ++rr) {
      const int row = wm + mt * 16 + q * 4 + rr;
      if (row < valid) {
        const size_t rbase = (size_t)(base + m0 + row) * NH;
#pragma unroll
        for (int nt = 0; nt < 4; ++nt) {
          const int col = n0 + wn + nt * 16 + l15;
          hbuf[rbase + col] = __float2bfloat16(fast_gelu(acc[mt][nt][rr] + bias[nt]));
        }
      }
    }
  }
}

// ---------------- grouped GEMM 2: out += p * (H @ w_down + b_down) ----------------
// single launch over id-tagged tile list; out zero-initialized; fp32 atomicAdd.
// NEW (this round): double-buffered 2-phase pipeline + split-K=2 over NH
// (grid.z) to lift occupancy from ~2.1 to ~4.2 blocks/CU. Bias added only by
// the ks==0 half; fp32 atomics make the split associativity-safe.
__global__ __launch_bounds__(512, 4) void moe_gemm_down(
    const __hip_bfloat16* __restrict__ hbuf,
    const __hip_bfloat16* __restrict__ wdnT,   // [E][D][H]
    const float* __restrict__ b_down,
    const int* __restrict__ slot_token, const float* __restrict__ slot_p,
    const int* __restrict__ cnt_ek, const int* __restrict__ off_ek,
    const int* __restrict__ ntiles, const int* __restrict__ tl_dn,
    float* __restrict__ out)
{
  if ((int)blockIdx.y >= ntiles[1]) return;
  const int tl = tl_dn[blockIdx.y];
  const int id = tl >> 16, mb = tl & 0xffff;
  const int e = id >> 1;
  const int cnt = cnt_ek[id];
  const int base = off_ek[id];
  const int m0 = mb * TM;
  const int n0 = blockIdx.x * TN;
  const int valid = (cnt - m0 < TM) ? (cnt - m0) : TM;
  const int ks = blockIdx.z;
  const int k_beg = ks * (NH / KS_DN);
  const int k_end = k_beg + (NH / KS_DN);

  __shared__ __align__(16) __hip_bfloat16 As0[TM * BK], As1[TM * BK];
  __shared__ __align__(16) __hip_bfloat16 Bs0[TN * BK], Bs1[TN * BK];

  const int tid = threadIdx.x;
  const int lane = tid & 63, wv = tid >> 6;

  const int raA = tid >> 2;
  const int kcA = ((tid & 3) ^ ((raA >> 1) & 3)) * 8;
  int srA = m0 + raA; if (srA >= cnt) srA = cnt - 1;
  const __hip_bfloat16* ga = hbuf + (size_t)(base + srA) * NH + kcA;
  const __hip_bfloat16* gb0;
  const __hip_bfloat16* gb1;
  {
    const int r0 = tid >> 2;
    const int k0 = ((tid & 3) ^ ((r0 >> 1) & 3)) * 8;
    gb0 = wdnT + ((size_t)e * ND + n0 + r0) * NH + k0;
    const int ci = tid + 512;
    const int r1 = ci >> 2;
    const int k1 = ((ci & 3) ^ ((r1 >> 1) & 3)) * 8;
    gb1 = wdnT + ((size_t)e * ND + n0 + r1) * NH + k1;
  }
  char* lA0 = (char*)As0 + tid * 16;
  char* lA1 = (char*)As1 + tid * 16;
  char* lB0 = (char*)Bs0 + tid * 16;
  char* lB1 = (char*)Bs1 + tid * 16;

  const int wm = (wv >> 2) * 64, wn = (wv & 3) * 64;
  const int l15 = lane & 15, q = lane >> 4;
  const int ssw = (q ^ ((l15 >> 1) & 3)) * 16;
  const char* rA0 = (const char*)As0 + (wm + l15) * 64 + ssw;
  const char* rA1 = (const char*)As1 + (wm + l15) * 64 + ssw;
  const char* rB0 = (const char*)Bs0 + (wn + l15) * 64 + ssw;
  const char* rB1 = (const char*)Bs1 + (wn + l15) * 64 + ssw;

  f32x4 acc[4][4] = {};

  auto STAGE = [&](char* sA, char* sB, int kk) {
    gl_lds16(ga + kk, sA);
    gl_lds16(gb0 + kk, sB);
    gl_lds16(gb1 + kk, sB + 8192);
  };
  auto COMPUTE = [&](const char* bA, const char* bB) {
    short8 af[4], bfr[4];
#pragma unroll
    for (int i = 0; i < 4; ++i) af[i]  = *(const short8*)(bA + i * 1024);
#pragma unroll
    for (int i = 0; i < 4; ++i) bfr[i] = *(const short8*)(bB + i * 1024);
#pragma unroll
    for (int mt = 0; mt < 4; ++mt)
#pragma unroll
      for (int nt = 0; nt < 4; ++nt)
        acc[mt][nt] = __builtin_amdgcn_mfma_f32_16x16x32_bf16(af[mt], bfr[nt], acc[mt][nt], 0, 0, 0);
  };

  STAGE(lA0, lB0, k_beg);
  __syncthreads();

  // (NH/KS_DN)/BK = 64 steps, unrolled by 2
  for (int kk = k_beg; kk < k_end; kk += 2 * BK) {
    STAGE(lA1, lB1, kk + BK);
    COMPUTE(rA0, rB0);
    __syncthreads();
    if (kk + 2 * BK < k_end) STAGE(lA0, lB0, kk + 2 * BK);
    COMPUTE(rA1, rB1);
    __syncthreads();
  }

  float bias[4];
#pragma unroll
  for (int nt = 0; nt < 4; ++nt)
    bias[nt] = (ks == 0) ? b_down[e * ND + n0 + wn + nt * 16 + l15] : 0.f;
#pragma unroll
  for (int mt = 0; mt < 4; ++mt) {
#pragma unroll
    for (int rr = 0; rr < 4; ++rr) {
      const int row = wm + mt * 16 + q * 4 + rr;
      if (row < valid) {
        const int slot = base + m0 + row;
        const int tok = slot_token[slot];
        const float p = slot_p[slot];
        const size_t obase = (size_t)tok * ND;
#pragma unroll
        for (int nt = 0; nt < 4; ++nt) {
          const int col = n0 + wn + nt * 16 + l15;
          atomicAdd(&out[obase + col], (acc[mt][nt][rr] + bias[nt]) * p);
        }
      }
    }
  }
}

// ---------------- launch ----------------
extern "C" void kernel_launch(void* const* d_in, const int* in_sizes, int n_in,
                              void* d_out, int out_size, void* d_ws, size_t ws_size,
                              hipStream_t stream) {
  (void)in_sizes; (void)n_in; (void)out_size; (void)ws_size;
  const float* x   = (const float*)d_in[0];
  const float* rw  = (const float*)d_in[1];
  const float* rb  = (const float*)d_in[2];
  const float* wup = (const float*)d_in[3];
  const float* bup = (const float*)d_in[4];
  const float* wdn = (const float*)d_in[5];
  const float* bdn = (const float*)d_in[6];
  float* out = (float*)d_out;

  char* ws = (char*)d_ws;
  __hip_bfloat16* xbf  = (__hip_bfloat16*)(ws + O_XBF);
  __hip_bfloat16* wupT = (__hip_bfloat16*)(ws + O_WUPT);
  __hip_bfloat16* wdnT = (__hip_bfloat16*)(ws + O_WDNT);
  __hip_bfloat16* hbuf = (__hip_bfloat16*)(ws + O_HBUF);
  int*   slot_token = (int*)(ws + O_STOK);
  float* slot_p     = (float*)(ws + O_SP);
  int*   topk_e     = (int*)(ws + O_TKE);
  float* topk_p     = (float*)(ws + O_TKP);
  int*   cnt_ek  = (int*)(ws + O_CTRL);
  int*   fill_ek = (int*)(ws + O_CTRL + 64);
  float* probsum = (float*)(ws + O_CTRL + 128);
  int*   off_ek  = (int*)(ws + O_CTRL + 192);
  int*   ntiles  = (int*)(ws + O_CTRL + 256);
  int*   tl_up   = (int*)(ws + O_TLUP);
  int*   tl_dn   = (int*)(ws + O_TLDN);

  hipMemsetAsync(ws + O_CTRL, 0, 272, stream);
  hipMemsetAsync(out, 0, (size_t)NT * ND * sizeof(float), stream);  // down-GEMM atomicAdd target

  // weight transposes (independent of router)
  moe_transpose_cast<<<dim3(NH / 64, ND / 64, NE), 256, 0, stream>>>(wup, wupT, ND, NH);
  moe_transpose_cast<<<dim3(ND / 64, NH / 64, NE), 256, 0, stream>>>(wdn, wdnT, NH, ND);

  // router (+ x->bf16), aux/offsets/tile-lists, scatter
  moe_router<<<256, 256, 0, stream>>>(x, rw, rb, xbf, out + (size_t)NT * ND + 1,
                                      topk_e, topk_p, cnt_ek, probsum);
  moe_finalize<<<1, 64, 0, stream>>>(cnt_ek, off_ek, probsum, out + (size_t)NT * ND,
                                     ntiles, tl_up, tl_dn);
  moe_scatter<<<NT / 256, 256, 0, stream>>>(topk_e, topk_p, off_ek, fill_ek, slot_token, slot_p);

  // grouped GEMMs (exact tile-list grids; blocks early-exit past device-side tile counts)
  moe_gemm_up<<<dim3(NH / TN, 136, 1), 512, 0, stream>>>(
      xbf, wupT, bup, slot_token, cnt_ek, off_ek, ntiles, tl_up, hbuf);
  moe_gemm_down<<<dim3(ND / TN, 144, KS_DN), 512, 0, stream>>>(
      hbuf, wdnT, bdn, slot_token, slot_p, cnt_ek, off_ek, ntiles, tl_dn, out);
}

// Round 2
// 868.706 us; speedup vs baseline: 1.0546x; 1.0177x over previous
//
#include <hip/hip_runtime.h>
#include <hip/hip_bf16.h>
#include <stdint.h>

// ---------------- problem constants ----------------
constexpr int NT = 8192;   // tokens (B*S)
constexpr int NE = 8;      // experts
constexpr int ND = 1024;   // d_model
constexpr int NH = 4096;   // hidden

constexpr int BM = 256;    // block tile M
constexpr int BN = 256;    // block tile N (8 waves: 2x4 of 128x64)
constexpr int BK = 32;     // K tile
constexpr int NBUF = 4;    // LDS ring depth (prefetch distance 2)
constexpr int KS_DN = 2;   // split-K factor for down GEMM (block-count balance)

typedef __attribute__((ext_vector_type(8))) short short8;  // 8 bf16 (4 VGPRs)
typedef __attribute__((ext_vector_type(4))) float f32x4;

// ---------------- workspace layout (bytes) ----------------
constexpr size_t O_XBF  = 0;                                   // x bf16 [NT][ND]
constexpr size_t O_WUPT = O_XBF  + (size_t)NT * ND * 2;        // w_up^T bf16 [E][H][D]
constexpr size_t O_WDNT = O_WUPT + (size_t)NE * NH * ND * 2;   // w_down^T bf16 [E][D][H]
constexpr size_t O_HBUF = O_WDNT + (size_t)NE * ND * NH * 2;   // hidden bf16 [NT*2][NH]
constexpr size_t O_STOK = O_HBUF + (size_t)NT * 2 * NH * 2;    // slot -> token
constexpr size_t O_SP   = O_STOK + (size_t)NT * 2 * 4;         // slot -> gate p
constexpr size_t O_TKE  = O_SP   + (size_t)NT * 2 * 4;         // token -> top2 experts
constexpr size_t O_TKP  = O_TKE  + (size_t)NT * 2 * 4;         // token -> top2 probs
constexpr size_t O_CTRL = O_TKP  + (size_t)NT * 2 * 4;
// ctrl: cnt[16]@0 fill[16]@64 probsum[8]@128 off[16]@192 ntiles[2]@256
constexpr size_t O_TLUP = O_CTRL + 272;                        // int[160] tile list up
constexpr size_t O_TLDN = O_TLUP + 160 * 4;                    // int[160] tile list down

__device__ __forceinline__ void gl_lds16(const void* g, void* l) {
  using GP = char __attribute__((address_space(1))) *;
  using LP = char __attribute__((address_space(3))) *;
  __builtin_amdgcn_global_load_lds((GP)(uintptr_t)g, (LP)(uint32_t)(uintptr_t)l, 16, 0, 0);
}

__device__ __forceinline__ float fast_gelu(float x) {
  float u  = 0.7978845608028654f * (x + 0.044715f * x * x * x);
  float ex = __expf(2.0f * u);
  float th = 1.0f - 2.0f / (ex + 1.0f);
  return 0.5f * x * (1.0f + th);
}

// ---------------- router: logits, softmax, top2, counts; also x->bf16 ----------------
__global__ __launch_bounds__(256) void moe_router(
    const float* __restrict__ x, const float* __restrict__ rw, const float* __restrict__ rb,
    __hip_bfloat16* __restrict__ xbf,
    float* __restrict__ probs_out, int* __restrict__ topk_e, float* __restrict__ topk_p,
    int* __restrict__ cnt_ek, float* __restrict__ probsum)
{
  __shared__ float ps[NE];
  __shared__ int cs[16];
  const int tid = threadIdx.x;
  if (tid < NE) ps[tid] = 0.f;
  if (tid < 16) cs[tid] = 0;
  __syncthreads();
  const int lane = tid & 63, wv = tid >> 6;
  for (int it = 0; it < 8; ++it) {
    const int t = blockIdx.x * 4 + wv + it * 1024;
    const float* xr = x + (size_t)t * ND;
    float acc[NE] = {};
#pragma unroll 4
    for (int j = 0; j < 16; ++j) {
      const int d = j * 64 + lane;
      const float xv = xr[d];
      xbf[(size_t)t * ND + d] = __float2bfloat16(xv);
      const float* w = rw + (size_t)d * NE;
#pragma unroll
      for (int ee = 0; ee < NE; ++ee) acc[ee] += xv * w[ee];
    }
#pragma unroll
    for (int ee = 0; ee < NE; ++ee)
#pragma unroll
      for (int off = 32; off >= 1; off >>= 1)
        acc[ee] += __shfl_down(acc[ee], off, 64);
    if (lane == 0) {
      float lg[NE];
#pragma unroll
      for (int ee = 0; ee < NE; ++ee) lg[ee] = acc[ee] + rb[ee];
      float mx = lg[0];
#pragma unroll
      for (int ee = 1; ee < NE; ++ee) mx = fmaxf(mx, lg[ee]);
      float s = 0.f, pe[NE];
#pragma unroll
      for (int ee = 0; ee < NE; ++ee) { pe[ee] = __expf(lg[ee] - mx); s += pe[ee]; }
      const float inv = 1.f / s;
#pragma unroll
      for (int ee = 0; ee < NE; ++ee) {
        const float pr = pe[ee] * inv;
        probs_out[(size_t)t * NE + ee] = pr;
        atomicAdd(&ps[ee], pr);
      }
      int i1 = 0; float l1 = lg[0];
#pragma unroll
      for (int ee = 1; ee < NE; ++ee) if (lg[ee] > l1) { l1 = lg[ee]; i1 = ee; }
      int i2 = 0; float l2 = -3.0e38f;
#pragma unroll
      for (int ee = 0; ee < NE; ++ee) if (ee != i1 && lg[ee] > l2) { l2 = lg[ee]; i2 = ee; }
      const float e2 = __expf(l2 - l1);
      const float dn = 1.f + e2;
      topk_e[t * 2]     = i1;  topk_e[t * 2 + 1] = i2;
      topk_p[t * 2]     = 1.f / dn;
      topk_p[t * 2 + 1] = e2 / dn;
      atomicAdd(&cs[i1 * 2], 1);
      atomicAdd(&cs[i2 * 2 + 1], 1);
    }
  }
  __syncthreads();
  if (tid < NE) atomicAdd(&probsum[tid], ps[tid]);
  if (tid < 16) atomicAdd(&cnt_ek[tid], cs[tid]);
}

// ---------------- offsets prefix + aux loss + tile lists (256-row GEMM tiles) ----------
__global__ void moe_finalize(const int* __restrict__ cnt_ek, int* __restrict__ off_ek,
                             const float* __restrict__ probsum, float* __restrict__ aux_out,
                             int* __restrict__ ntiles, int* __restrict__ tl_up,
                             int* __restrict__ tl_dn)
{
  __shared__ int c[16], off[16], uoff[8], ucnt[8], doff[16], dcnt[16];
  const int tid = threadIdx.x;
  if (tid < 16) c[tid] = cnt_ek[tid];
  __syncthreads();
  if (tid == 0) {
    int run = 0;
    for (int i = 0; i < 16; ++i) { off[i] = run; run += c[i]; }
    int ur = 0;
    for (int e = 0; e < NE; ++e) {
      ucnt[e] = (c[2 * e] + c[2 * e + 1] + BM - 1) / BM;
      uoff[e] = ur; ur += ucnt[e];
    }
    ntiles[0] = ur;
    int dr = 0;
    for (int i = 0; i < 16; ++i) {
      dcnt[i] = (c[i] + BM - 1) / BM;
      doff[i] = dr; dr += dcnt[i];
    }
    ntiles[1] = dr;
    float aux = 0.f;
    for (int e = 0; e < NE; ++e) {
      float frac = (float)(c[2 * e] + c[2 * e + 1]) / (float)(NT * 2);
      aux += frac * (probsum[e] / (float)NT);
    }
    aux_out[0] = (float)NE * aux * 0.01f;
  }
  __syncthreads();
  if (tid < 16) off_ek[tid] = off[tid];
  if (tid < 8)
    for (int mb = 0; mb < ucnt[tid]; ++mb) tl_up[uoff[tid] + mb] = (tid << 16) | mb;
  if (tid >= 32 && tid < 48) {
    const int i = tid - 32;
    for (int mb = 0; mb < dcnt[i]; ++mb) tl_dn[doff[i] + mb] = (i << 16) | mb;
  }
}

// ---------------- scatter: per-block LDS histogram, 16 global atomics/block ----------
__global__ __launch_bounds__(256) void moe_scatter(
    const int* __restrict__ topk_e, const float* __restrict__ topk_p,
    const int* __restrict__ off_ek, int* __restrict__ fill_ek,
    int* __restrict__ slot_token, float* __restrict__ slot_p)
{
  __shared__ int lc[16], gb[16], offs[16];
  const int tid = threadIdx.x;
  if (tid < 16) lc[tid] = 0;
  __syncthreads();
  const int t = blockIdx.x * 256 + tid;
  const int id0 = topk_e[t * 2] * 2;
  const int id1 = topk_e[t * 2 + 1] * 2 + 1;
  atomicAdd(&lc[id0], 1);
  atomicAdd(&lc[id1], 1);
  __syncthreads();
  if (tid < 16) {
    gb[tid] = atomicAdd(&fill_ek[tid], lc[tid]);
    offs[tid] = off_ek[tid];
    lc[tid] = 0;
  }
  __syncthreads();
  {
    const int r = atomicAdd(&lc[id0], 1);
    const int slot = offs[id0] + gb[id0] + r;
    slot_token[slot] = t;
    slot_p[slot] = topk_p[t * 2];
  }
  {
    const int r = atomicAdd(&lc[id1], 1);
    const int slot = offs[id1] + gb[id1] + r;
    slot_token[slot] = t;
    slot_p[slot] = topk_p[t * 2 + 1];
  }
}

// ---------------- transpose+cast: in fp32 [E][A][B] -> out bf16 [E][B][A] ----------------
__global__ __launch_bounds__(256) void moe_transpose_cast(
    const float* __restrict__ in, __hip_bfloat16* __restrict__ outp, int Adim, int Bdim)
{
  __shared__ unsigned short tile[64 * 66];
  const int e = blockIdx.z;
  const int b0 = blockIdx.x * 64, a0 = blockIdx.y * 64;
  const float* ip = in + (size_t)e * Adim * Bdim + (size_t)a0 * Bdim + b0;
  const int c4 = (threadIdx.x & 15) * 4;
  const int r0 = threadIdx.x >> 4;
#pragma unroll
  for (int i = 0; i < 4; ++i) {
    const int r = r0 + i * 16;
    const float4 v = *(const float4*)(ip + (size_t)r * Bdim + c4);
    ushort4 u;
    u.x = __hip_bfloat16_raw(__float2bfloat16(v.x)).x;
    u.y = __hip_bfloat16_raw(__float2bfloat16(v.y)).x;
    u.z = __hip_bfloat16_raw(__float2bfloat16(v.z)).x;
    u.w = __hip_bfloat16_raw(__float2bfloat16(v.w)).x;
    *(ushort4*)&tile[r * 66 + c4] = u;
  }
  __syncthreads();
  unsigned short* op = (unsigned short*)outp + (size_t)e * Bdim * Adim + (size_t)b0 * Adim + a0;
  const int cc  = threadIdx.x >> 2;
  const int rr0 = (threadIdx.x & 3) * 16;
  unsigned short u[16];
#pragma unroll
  for (int i = 0; i < 16; ++i) u[i] = tile[(rr0 + i) * 66 + cc];
  *(short8*)(op + (size_t)cc * Adim + rr0)     = *(short8*)&u[0];
  *(short8*)(op + (size_t)cc * Adim + rr0 + 8) = *(short8*)&u[8];
}

// ============================================================================
// Grouped GEMMs, new structure (this round):
//   256x256 tile, BK=32, 8 waves (2Mx4N; 128x64/wave; 32 MFMA/wave/K-tile),
//   4-deep LDS ring (4 x (16KB A + 16KB B) = 128 KB), prefetch distance 2,
//   ONE raw s_barrier per K-tile, counted s_waitcnt vmcnt(8) (T4: loads stay
//   in flight across barriers; never drained to 0 in steady state),
//   s_setprio(1) around the MFMA cluster (T5).
// Ring-race check: iter t reads buf[t%4]; fastest wave (<=1 iter ahead) writes
// buf[(t+3)%4] -- always distinct. Chunk XOR swizzle (measured 0 conflicts)
// carried over: slot (row,c) holds global chunk c ^ ((row>>1)&3).
// ============================================================================

// ---------------- grouped GEMM 1: H = gelu(X_sel @ w_up + b_up) ----------------
__global__ __launch_bounds__(512, 2) void moe_gemm_up(
    const __hip_bfloat16* __restrict__ xbf,
    const __hip_bfloat16* __restrict__ wupT,   // [E][H][D]
    const float* __restrict__ b_up,
    const int* __restrict__ slot_token,
    const int* __restrict__ cnt_ek, const int* __restrict__ off_ek,
    const int* __restrict__ ntiles, const int* __restrict__ tl_up,
    __hip_bfloat16* __restrict__ hbuf)          // [NT*2][NH]
{
  if ((int)blockIdx.y >= ntiles[0]) return;
  const int tl = tl_up[blockIdx.y];
  const int e = tl >> 16, mb = tl & 0xffff;
  const int cnt = cnt_ek[2 * e] + cnt_ek[2 * e + 1];
  const int base = off_ek[2 * e];
  const int m0 = mb * BM;
  const int n0 = blockIdx.x * BN;
  const int valid = (cnt - m0 < BM) ? (cnt - m0) : BM;

  // 4-deep ring: per buffer A 256x32 bf16 (16KB) + B 256x32 bf16 (16KB)
  __shared__ __align__(16) __hip_bfloat16 As[NBUF][BM * BK];   // 64 KB
  __shared__ __align__(16) __hip_bfloat16 Bs[NBUF][BN * BK];   // 64 KB

  const int tid = threadIdx.x;
  const int lane = tid & 63, wv = tid >> 6;

  // staging: A 1024 chunks of 16B (2/thread), B 1024 chunks (2/thread)
  const int r0c = tid >> 2;                 // rows 0..127
  const int k0c = ((tid & 3) ^ ((r0c >> 1) & 3)) * 8;
  const int r1c = r0c + 128;                // rows 128..255
  const int k1c = ((tid & 3) ^ ((r1c >> 1) & 3)) * 8;
  int srA0 = m0 + r0c; if (srA0 >= cnt) srA0 = cnt - 1;
  int srA1 = m0 + r1c; if (srA1 >= cnt) srA1 = cnt - 1;
  const __hip_bfloat16* gA0 = xbf + (size_t)slot_token[base + srA0] * ND + k0c;
  const __hip_bfloat16* gA1 = xbf + (size_t)slot_token[base + srA1] * ND + k1c;
  const __hip_bfloat16* gB0 = wupT + ((size_t)e * NH + n0 + r0c) * ND + k0c;
  const __hip_bfloat16* gB1 = wupT + ((size_t)e * NH + n0 + r1c) * ND + k1c;

  auto STAGE = [&](int bi, int kk) {
    char* sA = (char*)&As[bi][0] + tid * 16;
    char* sB = (char*)&Bs[bi][0] + tid * 16;
    gl_lds16(gA0 + kk, sA);
    gl_lds16(gA1 + kk, sA + 8192);
    gl_lds16(gB0 + kk, sB);
    gl_lds16(gB1 + kk, sB + 8192);
  };

  const int wm = (wv >> 2) * 128, wn = (wv & 3) * 64;
  const int l15 = lane & 15, q = lane >> 4;
  const int ssw = (q ^ ((l15 >> 1) & 3)) * 16;

  f32x4 acc[8][4] = {};

  auto COMPUTE = [&](int bi) {
    const char* bA = (const char*)&As[bi][0] + (wm + l15) * 64 + ssw;
    const char* bB = (const char*)&Bs[bi][0] + (wn + l15) * 64 + ssw;
    short8 af[8], bfr[4];
#pragma unroll
    for (int i = 0; i < 8; ++i) af[i]  = *(const short8*)(bA + i * 1024);
#pragma unroll
    for (int i = 0; i < 4; ++i) bfr[i] = *(const short8*)(bB + i * 1024);
    __builtin_amdgcn_s_setprio(1);
#pragma unroll
    for (int mt = 0; mt < 8; ++mt)
#pragma unroll
      for (int nt = 0; nt < 4; ++nt)
        acc[mt][nt] = __builtin_amdgcn_mfma_f32_16x16x32_bf16(af[mt], bfr[nt], acc[mt][nt], 0, 0, 0);
    __builtin_amdgcn_s_setprio(0);
  };

  constexpr int KT = ND / BK;   // 32
  STAGE(0, 0);
  STAGE(1, BK);
  for (int t = 0; t < KT; ++t) {
    if (t + 2 < KT) {
      STAGE((t + 2) & 3, (t + 2) * BK);
      asm volatile("s_waitcnt vmcnt(8)" ::: "memory");   // drain tile t; t+1,t+2 in flight
    } else if (t + 2 == KT) {
      asm volatile("s_waitcnt vmcnt(4)" ::: "memory");
    } else {
      asm volatile("s_waitcnt vmcnt(0)" ::: "memory");
    }
    __builtin_amdgcn_s_barrier();
    __builtin_amdgcn_sched_barrier(0);
    COMPUTE(t & 3);
  }

  float bias[4];
#pragma unroll
  for (int nt = 0; nt < 4; ++nt) bias[nt] = b_up[e * NH + n0 + wn + nt * 16 + l15];
#pragma unroll
  for (int mt = 0; mt < 8; ++mt) {
#pragma unroll
    for (int rr = 0; rr < 4; ++rr) {
      const int row = wm + mt * 16 + q * 4 + rr;
      if (row < valid) {
        const size_t rbase = (size_t)(base + m0 + row) * NH;
#pragma unroll
        for (int nt = 0; nt < 4; ++nt) {
          const int col = n0 + wn + nt * 16 + l15;
          hbuf[rbase + col] = __float2bfloat16(fast_gelu(acc[mt][nt][rr] + bias[nt]));
        }
      }
    }
  }
}

// ---------------- grouped GEMM 2: out += p * (H @ w_down + b_down) ----------------
// split-K=2 over NH (grid.z); bias added by ks==0 half; fp32 atomics.
__global__ __launch_bounds__(512, 2) void moe_gemm_down(
    const __hip_bfloat16* __restrict__ hbuf,
    const __hip_bfloat16* __restrict__ wdnT,   // [E][D][H]
    const float* __restrict__ b_down,
    const int* __restrict__ slot_token, const float* __restrict__ slot_p,
    const int* __restrict__ cnt_ek, const int* __restrict__ off_ek,
    const int* __restrict__ ntiles, const int* __restrict__ tl_dn,
    float* __restrict__ out)
{
  if ((int)blockIdx.y >= ntiles[1]) return;
  const int tl = tl_dn[blockIdx.y];
  const int id = tl >> 16, mb = tl & 0xffff;
  const int e = id >> 1;
  const int cnt = cnt_ek[id];
  const int base = off_ek[id];
  const int m0 = mb * BM;
  const int n0 = blockIdx.x * BN;
  const int valid = (cnt - m0 < BM) ? (cnt - m0) : BM;
  const int ks = blockIdx.z;
  const int k_beg = ks * (NH / KS_DN);

  __shared__ __align__(16) __hip_bfloat16 As[NBUF][BM * BK];   // 64 KB
  __shared__ __align__(16) __hip_bfloat16 Bs[NBUF][BN * BK];   // 64 KB

  const int tid = threadIdx.x;
  const int lane = tid & 63, wv = tid >> 6;

  const int r0c = tid >> 2;
  const int k0c = ((tid & 3) ^ ((r0c >> 1) & 3)) * 8;
  const int r1c = r0c + 128;
  const int k1c = ((tid & 3) ^ ((r1c >> 1) & 3)) * 8;
  int srA0 = m0 + r0c; if (srA0 >= cnt) srA0 = cnt - 1;
  int srA1 = m0 + r1c; if (srA1 >= cnt) srA1 = cnt - 1;
  const __hip_bfloat16* gA0 = hbuf + (size_t)(base + srA0) * NH + k0c;
  const __hip_bfloat16* gA1 = hbuf + (size_t)(base + srA1) * NH + k1c;
  const __hip_bfloat16* gB0 = wdnT + ((size_t)e * ND + n0 + r0c) * NH + k0c;
  const __hip_bfloat16* gB1 = wdnT + ((size_t)e * ND + n0 + r1c) * NH + k1c;

  auto STAGE = [&](int bi, int kk) {
    char* sA = (char*)&As[bi][0] + tid * 16;
    char* sB = (char*)&Bs[bi][0] + tid * 16;
    gl_lds16(gA0 + kk, sA);
    gl_lds16(gA1 + kk, sA + 8192);
    gl_lds16(gB0 + kk, sB);
    gl_lds16(gB1 + kk, sB + 8192);
  };

  const int wm = (wv >> 2) * 128, wn = (wv & 3) * 64;
  const int l15 = lane & 15, q = lane >> 4;
  const int ssw = (q ^ ((l15 >> 1) & 3)) * 16;

  f32x4 acc[8][4] = {};

  auto COMPUTE = [&](int bi) {
    const char* bA = (const char*)&As[bi][0] + (wm + l15) * 64 + ssw;
    const char* bB = (const char*)&Bs[bi][0] + (wn + l15) * 64 + ssw;
    short8 af[8], bfr[4];
#pragma unroll
    for (int i = 0; i < 8; ++i) af[i]  = *(const short8*)(bA + i * 1024);
#pragma unroll
    for (int i = 0; i < 4; ++i) bfr[i] = *(const short8*)(bB + i * 1024);
    __builtin_amdgcn_s_setprio(1);
#pragma unroll
    for (int mt = 0; mt < 8; ++mt)
#pragma unroll
      for (int nt = 0; nt < 4; ++nt)
        acc[mt][nt] = __builtin_amdgcn_mfma_f32_16x16x32_bf16(af[mt], bfr[nt], acc[mt][nt], 0, 0, 0);
    __builtin_amdgcn_s_setprio(0);
  };

  constexpr int KT = (NH / KS_DN) / BK;   // 64
  STAGE(0, k_beg);
  STAGE(1, k_beg + BK);
  for (int t = 0; t < KT; ++t) {
    if (t + 2 < KT) {
      STAGE((t + 2) & 3, k_beg + (t + 2) * BK);
      asm volatile("s_waitcnt vmcnt(8)" ::: "memory");
    } else if (t + 2 == KT) {
      asm volatile("s_waitcnt vmcnt(4)" ::: "memory");
    } else {
      asm volatile("s_waitcnt vmcnt(0)" ::: "memory");
    }
    __builtin_amdgcn_s_barrier();
    __builtin_amdgcn_sched_barrier(0);
    COMPUTE(t & 3);
  }

  float bias[4];
#pragma unroll
  for (int nt = 0; nt < 4; ++nt)
    bias[nt] = (ks == 0) ? b_down[e * ND + n0 + wn + nt * 16 + l15] : 0.f;
#pragma unroll
  for (int mt = 0; mt < 8; ++mt) {
#pragma unroll
    for (int rr = 0; rr < 4; ++rr) {
      const int row = wm + mt * 16 + q * 4 + rr;
      if (row < valid) {
        const int slot = base + m0 + row;
        const int tok = slot_token[slot];
        const float p = slot_p[slot];
        const size_t obase = (size_t)tok * ND;
#pragma unroll
        for (int nt = 0; nt < 4; ++nt) {
          const int col = n0 + wn + nt * 16 + l15;
          atomicAdd(&out[obase + col], (acc[mt][nt][rr] + bias[nt]) * p);
        }
      }
    }
  }
}

// ---------------- launch ----------------
extern "C" void kernel_launch(void* const* d_in, const int* in_sizes, int n_in,
                              void* d_out, int out_size, void* d_ws, size_t ws_size,
                              hipStream_t stream) {
  (void)in_sizes; (void)n_in; (void)out_size; (void)ws_size;
  const float* x   = (const float*)d_in[0];
  const float* rw  = (const float*)d_in[1];
  const float* rb  = (const float*)d_in[2];
  const float* wup = (const float*)d_in[3];
  const float* bup = (const float*)d_in[4];
  const float* wdn = (const float*)d_in[5];
  const float* bdn = (const float*)d_in[6];
  float* out = (float*)d_out;

  char* ws = (char*)d_ws;
  __hip_bfloat16* xbf  = (__hip_bfloat16*)(ws + O_XBF);
  __hip_bfloat16* wupT = (__hip_bfloat16*)(ws + O_WUPT);
  __hip_bfloat16* wdnT = (__hip_bfloat16*)(ws + O_WDNT);
  __hip_bfloat16* hbuf = (__hip_bfloat16*)(ws + O_HBUF);
  int*   slot_token = (int*)(ws + O_STOK);
  float* slot_p     = (float*)(ws + O_SP);
  int*   topk_e     = (int*)(ws + O_TKE);
  float* topk_p     = (float*)(ws + O_TKP);
  int*   cnt_ek  = (int*)(ws + O_CTRL);
  int*   fill_ek = (int*)(ws + O_CTRL + 64);
  float* probsum = (float*)(ws + O_CTRL + 128);
  int*   off_ek  = (int*)(ws + O_CTRL + 192);
  int*   ntiles  = (int*)(ws + O_CTRL + 256);
  int*   tl_up   = (int*)(ws + O_TLUP);
  int*   tl_dn   = (int*)(ws + O_TLDN);

  hipMemsetAsync(ws + O_CTRL, 0, 272, stream);
  hipMemsetAsync(out, 0, (size_t)NT * ND * sizeof(float), stream);  // down-GEMM atomicAdd target

  // weight transposes (independent of router)
  moe_transpose_cast<<<dim3(NH / 64, ND / 64, NE), 256, 0, stream>>>(wup, wupT, ND, NH);
  moe_transpose_cast<<<dim3(ND / 64, NH / 64, NE), 256, 0, stream>>>(wdn, wdnT, NH, ND);

  // router (+ x->bf16), aux/offsets/tile-lists, scatter
  moe_router<<<256, 256, 0, stream>>>(x, rw, rb, xbf, out + (size_t)NT * ND + 1,
                                      topk_e, topk_p, cnt_ek, probsum);
  moe_finalize<<<1, 64, 0, stream>>>(cnt_ek, off_ek, probsum, out + (size_t)NT * ND,
                                     ntiles, tl_up, tl_dn);
  moe_scatter<<<NT / 256, 256, 0, stream>>>(topk_e, topk_p, off_ek, fill_ek, slot_token, slot_p);

  // grouped GEMMs. Worst-case tile counts: up <= ceil(16384/256)+7 = 71,
  // down <= 64+15 = 79; blocks early-exit past device-side tile counts.
  moe_gemm_up<<<dim3(NH / BN, 72, 1), 512, 0, stream>>>(
      xbf, wupT, bup, slot_token, cnt_ek, off_ek, ntiles, tl_up, hbuf);
  moe_gemm_down<<<dim3(ND / BN, 80, KS_DN), 512, 0, stream>>>(
      hbuf, wdnT, bdn, slot_token, slot_p, cnt_ek, off_ek, ntiles, tl_dn, out);
}